// Round 7
// baseline (302.722 us; speedup 1.0000x reference)
//
#include <hip/hip_runtime.h>
#include <cstddef>

// Problem constants
#define B_   8
#define C4_  256
#define C5_  512
#define OC_  256
#define FR_  128
#define H_   64
#define W_   64
#define HW_  4096

typedef unsigned short u16;
typedef __bf16 bf16x8 __attribute__((ext_vector_type(8)));
typedef float floatx4 __attribute__((ext_vector_type(4)));

__device__ __forceinline__ u16 f2b(float x) {
    unsigned int u = __float_as_uint(x);
    return (u16)((u + 0x7FFFu + ((u >> 16) & 1u)) >> 16);
}
__device__ __forceinline__ float b2f(u16 x) {
    return __uint_as_float(((unsigned int)x) << 16);
}

// ---------------------------------------------------------------------------
// Merged weight packs + W_eff:
//  blocks 0..3071: A3[tap][oc][c] from w3; A1; Wtf  (786432 elems)
//  blocks 3072..3327: W_eff[oc][c] = sum_f w_proj[oc][f]*w_reshape[f][c]
// ---------------------------------------------------------------------------
__global__ __launch_bounds__(256) void pack_misc(
    const float* __restrict__ w3, const float* __restrict__ w1,
    const float* __restrict__ wtf,
    const float* __restrict__ wp, const float* __restrict__ wr,
    u16* __restrict__ A3, u16* __restrict__ A1, u16* __restrict__ Wtf,
    u16* __restrict__ Weff)
{
    if (blockIdx.x < 3072) {
        int i = blockIdx.x * 256 + threadIdx.x;
        if (i < 589824) {
            int tap = i >> 16;
            int r   = i & 65535;
            int oc  = r >> 8, c = r & 255;
            A3[i] = f2b(w3[((size_t)oc * 256 + c) * 9 + tap]);
        } else if (i < 720896) {
            int j = i - 589824;
            A1[j] = f2b(w1[j]);
        } else {
            int j = i - 720896;
            Wtf[j] = f2b(wtf[j]);
        }
    } else {
        const int oc = blockIdx.x - 3072, c = threadIdx.x;
        float s = 0.f;
        for (int f = 0; f < 128; ++f)
            s += wp[oc * 128 + f] * wr[f * 256 + c];
        Weff[oc * 256 + c] = f2b(s);
    }
}

// ---------------------------------------------------------------------------
// Merged feature packs: c4 NCHW f32 -> NHWC bf16 (x<64), c5 likewise (x>=64).
// grid (96, 8), block 256.
// ---------------------------------------------------------------------------
__global__ __launch_bounds__(256) void pack_feat(const float* __restrict__ in4,
                                                 const float* __restrict__ in5,
                                                 u16* __restrict__ c4t,
                                                 u16* __restrict__ c5t)
{
    __shared__ float sT[16448];
    const int t = threadIdx.x, b = blockIdx.y;
    if (blockIdx.x < 64) {
        const int h = blockIdx.x;
        const int w = t & 63, cg = t >> 6;          // cg 0..3
        for (int i = 0; i < 64; ++i) {
            int c = cg * 64 + i;
            sT[w * 257 + c] = in4[(((size_t)b * 256 + c) * 64 + h) * 64 + w];
        }
        __syncthreads();
        for (int i = 0; i < 16; ++i) {
            int ww = cg * 16 + i;
            int c0 = (t & 63) * 4;
            ushort4 v;
            v.x = f2b(sT[ww * 257 + c0]);
            v.y = f2b(sT[ww * 257 + c0 + 1]);
            v.z = f2b(sT[ww * 257 + c0 + 2]);
            v.w = f2b(sT[ww * 257 + c0 + 3]);
            *(ushort4*)&c4t[(((size_t)b * 64 + h) * 64 + ww) * 256 + c0] = v;
        }
    } else {
        const int h2 = blockIdx.x - 64;
        const int w = t & 31, cg = t >> 5;          // cg 0..7
        for (int i = 0; i < 64; ++i) {
            int c = cg * 64 + i;
            sT[w * 513 + c] = in5[(((size_t)b * 512 + c) * 32 + h2) * 32 + w];
        }
        __syncthreads();
        for (int i = 0; i < 16; ++i) {
            int id = i * 256 + t;                    // < 4096
            int ww = id >> 7, c0 = (id & 127) * 4;
            ushort4 v;
            v.x = f2b(sT[ww * 513 + c0]);
            v.y = f2b(sT[ww * 513 + c0 + 1]);
            v.z = f2b(sT[ww * 513 + c0 + 2]);
            v.w = f2b(sT[ww * 513 + c0 + 3]);
            *(ushort4*)&c5t[(((size_t)b * 32 + h2) * 32 + ww) * 512 + c0] = v;
        }
    }
}

// ---------------------------------------------------------------------------
// MFMA implicit-GEMM: fusedb(bf16 NHWC) = conv3x3(c4) + conv1x1(c5_up)
// grid 1024 (1-D, XCD-swizzled: each XCD owns one batch image), block 256
// = 4 waves, each wave 32oc x 64px.  Tile: 128 oc x 64 px (one row).
// LDS: single 3x66x64ch buffer (25.3 KB) -> 4 blocks/CU, 4 waves/SIMD.
// A3/A1 and c5 B-fragments read straight from global (L2-resident).
// ---------------------------------------------------------------------------
__global__ __launch_bounds__(256, 4) void fuse_mfma(
    const u16* __restrict__ c4t, const u16* __restrict__ c5t,
    const u16* __restrict__ A3, const u16* __restrict__ A1,
    u16* __restrict__ fusedb)
{
    extern __shared__ char smem[];                  // 198 px * 128 B = 25344 B

    const int t   = threadIdx.x;
    // XCD swizzle: consecutive 128-block chunk -> one XCD -> one batch image
    const int lin = blockIdx.x;
    const int d   = ((lin & 7) << 7) + (lin >> 3);
    const int b   = d >> 7;                         // batch image
    const int oc0 = ((d >> 6) & 1) * 128;           // oc half
    const int h   = d & 63;                         // output row

    const int l   = t & 63;
    const int wm  = t >> 6;                         // wave id 0..3: 32-oc slice
    const int lr  = l & 15;
    const int ks  = l >> 4;                         // 0..3

    floatx4 acc[2][4];
    #pragma unroll
    for (int m = 0; m < 2; ++m)
        #pragma unroll
        for (int n = 0; n < 4; ++n)
            acc[m][n] = (floatx4){0.f, 0.f, 0.f, 0.f};

    // ------------------- conv3x3: 4 chunks of 64 ch -------------------
    for (int c0 = 0; c0 < 256; c0 += 64) {
        __syncthreads();
        // stage rows h-1..h+1, cols -1..64, channels c0..c0+63 (swizzled)
        for (int i = t; i < 1584; i += 256) {
            int px  = i >> 3, seg = i & 7;
            int gh  = h - 1 + px / 66;
            int gw  = (px % 66) - 1;
            int4 v = {0, 0, 0, 0};
            if (gh >= 0 && gh < 64 && gw >= 0 && gw < 64)
                v = *(const int4*)(c4t + ((((size_t)b * 64 + gh) * 64 + gw) << 8) + c0 + seg * 8);
            *(int4*)(smem + px * 128 + ((seg ^ (px & 7)) << 4)) = v;
        }
        __syncthreads();

        #pragma unroll
        for (int ky = 0; ky < 3; ++ky) {
            #pragma unroll
            for (int kx = 0; kx < 3; ++kx) {
                const int tap = ky * 3 + kx;
                #pragma unroll
                for (int kk = 0; kk < 2; ++kk) {
                    bf16x8 a[2], bb[4];
                    #pragma unroll
                    for (int m = 0; m < 2; ++m) {
                        const int oc = oc0 + wm * 32 + m * 16 + lr;
                        a[m] = *(const bf16x8*)(A3 + (((size_t)tap * 256 + oc) * 256 + c0 + kk * 32 + ks * 8));
                    }
                    #pragma unroll
                    for (int n = 0; n < 4; ++n) {
                        const int pix = ky * 66 + n * 16 + lr + kx;
                        const int slot = ((kk << 2) + ks) ^ (pix & 7);
                        bb[n] = *(const bf16x8*)(smem + pix * 128 + slot * 16);
                    }
                    #pragma unroll
                    for (int m = 0; m < 2; ++m)
                        #pragma unroll
                        for (int n = 0; n < 4; ++n)
                            acc[m][n] = __builtin_amdgcn_mfma_f32_16x16x32_bf16(
                                a[m], bb[n], acc[m][n], 0, 0, 0);
                }
            }
        }
    }

    // ------------------- conv1x1 over c5_up: 16 chunks of 32 ch -------------------
    const int h2 = h >> 1;
    for (int cc = 0; cc < 512; cc += 32) {
        bf16x8 a[2], bb[4];
        #pragma unroll
        for (int m = 0; m < 2; ++m) {
            const int oc = oc0 + wm * 32 + m * 16 + lr;
            a[m] = *(const bf16x8*)(A1 + ((size_t)oc * 512 + cc + ks * 8));
        }
        #pragma unroll
        for (int n = 0; n < 4; ++n) {
            const int w2 = (n * 16 + lr) >> 1;
            bb[n] = *(const bf16x8*)(c5t + ((((size_t)b * 32 + h2) * 32 + w2) << 9) + cc + ks * 8);
        }
        #pragma unroll
        for (int m = 0; m < 2; ++m)
            #pragma unroll
            for (int n = 0; n < 4; ++n)
                acc[m][n] = __builtin_amdgcn_mfma_f32_16x16x32_bf16(
                    a[m], bb[n], acc[m][n], 0, 0, 0);
    }

    // ------------------- epilogue: bf16 NHWC -------------------
    #pragma unroll
    for (int n = 0; n < 4; ++n) {
        const int w = n * 16 + lr;
        const size_t base = (((size_t)b * 64 + h) * 64 + w) * 256;
        #pragma unroll
        for (int m = 0; m < 2; ++m) {
            const int oc = oc0 + wm * 32 + m * 16 + ks * 4;
            ushort4 v;
            v.x = f2b(acc[m][n][0]);
            v.y = f2b(acc[m][n][1]);
            v.z = f2b(acc[m][n][2]);
            v.w = f2b(acc[m][n][3]);
            *(ushort4*)&fusedb[base + oc] = v;
        }
    }
}

// ---------------------------------------------------------------------------
// Concatenated 1x1 GEMM from fusedb (bf16 NHWC), no LDS staging:
//   oct 0,1: yb   = Wtf  @ fused  (bf16 NHWC) + BN sums
//   oct 2,3: outb = Weff @ fused  (bf16 NHWC)
// grid (256 pxtiles, 4 octiles), block 256 = 4 waves (2x2).
// ---------------------------------------------------------------------------
__global__ __launch_bounds__(256) void gemm_cat(
    const u16* __restrict__ Bx, const u16* __restrict__ Wtf,
    const u16* __restrict__ Weff,
    u16* __restrict__ yb, u16* __restrict__ outb, float* __restrict__ sums)
{
    __shared__ float lsum[128], lsq[128];

    const int t = threadIdx.x;
    const int pxt = blockIdx.x;
    const int oct = blockIdx.y;
    const bool isY = (oct < 2);
    const u16* W = isY ? Wtf : Weff;
    u16* dst = isY ? yb : outb;
    const int oc0 = (oct & 1) * 128;
    const size_t pxg0 = (size_t)pxt * 128;

    const int l = t & 63, wid = t >> 6;
    const int wm = wid >> 1, wn = wid & 1;
    const int lr = l & 15, ks = l >> 4;

    floatx4 acc[4][4];
    #pragma unroll
    for (int m = 0; m < 4; ++m)
        #pragma unroll
        for (int n = 0; n < 4; ++n)
            acc[m][n] = (floatx4){0.f, 0.f, 0.f, 0.f};

    const u16* Wp = W + (size_t)(oc0 + wm * 64 + lr) * 256 + ks * 8;
    const u16* Bp = Bx + (pxg0 + wn * 64 + lr) * 256 + ks * 8;

    for (int c0 = 0; c0 < 256; c0 += 32) {
        bf16x8 a[4], bb[4];
        #pragma unroll
        for (int m = 0; m < 4; ++m)
            a[m] = *(const bf16x8*)(Wp + (size_t)m * 16 * 256 + c0);
        #pragma unroll
        for (int n = 0; n < 4; ++n)
            bb[n] = *(const bf16x8*)(Bp + (size_t)n * 16 * 256 + c0);
        #pragma unroll
        for (int m = 0; m < 4; ++m)
            #pragma unroll
            for (int n = 0; n < 4; ++n)
                acc[m][n] = __builtin_amdgcn_mfma_f32_16x16x32_bf16(
                    a[m], bb[n], acc[m][n], 0, 0, 0);
    }

    // epilogue: bf16 NHWC
    #pragma unroll
    for (int n = 0; n < 4; ++n) {
        const size_t px = pxg0 + wn * 64 + n * 16 + lr;
        #pragma unroll
        for (int m = 0; m < 4; ++m) {
            const int oc = oc0 + wm * 64 + m * 16 + ks * 4;
            ushort4 v;
            v.x = f2b(acc[m][n][0]);
            v.y = f2b(acc[m][n][1]);
            v.z = f2b(acc[m][n][2]);
            v.w = f2b(acc[m][n][3]);
            *(ushort4*)&dst[px * 256 + oc] = v;
        }
    }

    if (isY) {
        if (t < 128) { lsum[t] = 0.f; lsq[t] = 0.f; }
        __syncthreads();
        #pragma unroll
        for (int m = 0; m < 4; ++m) {
            #pragma unroll
            for (int r = 0; r < 4; ++r) {
                float s = 0.f, q = 0.f;
                #pragma unroll
                for (int n = 0; n < 4; ++n) {
                    float v = acc[m][n][r];
                    s += v; q += v * v;
                }
                #pragma unroll
                for (int off = 1; off < 16; off <<= 1) {
                    s += __shfl_xor(s, off);
                    q += __shfl_xor(q, off);
                }
                if (lr == 0) {
                    const int ocl = wm * 64 + m * 16 + ks * 4 + r;
                    atomicAdd(&lsum[ocl], s);
                    atomicAdd(&lsq[ocl], q);
                }
            }
        }
        __syncthreads();
        if (t < 128) {
            atomicAdd(&sums[oc0 + t], lsum[t]);
            atomicAdd(&sums[256 + oc0 + t], lsq[t]);
        }
    }
}

// ---------------------------------------------------------------------------
__global__ void bn_finalize(const float* __restrict__ sums,
                            const float* __restrict__ gamma,
                            const float* __restrict__ beta,
                            float* __restrict__ ab)
{
    int c = threadIdx.x;
    const float n = (float)(B_ * HW_);
    float mu  = sums[c] / n;
    float var = sums[256 + c] / n - mu * mu;
    float a = gamma[c] * rsqrtf(var + 1e-5f);
    ab[c]       = a;
    ab[256 + c] = beta[c] - mu * a;
}

// ---------------------------------------------------------------------------
// Merged adaptive pools: cg<64 -> pool4 from c4; else pool5 from c5 upsampled.
// grid (3, 192, 8), block 256 = 4ch x 64w
// ---------------------------------------------------------------------------
__global__ __launch_bounds__(256) void pool_both(const float* __restrict__ in4,
                                                 const float* __restrict__ in5,
                                                 float* __restrict__ pool4,
                                                 float* __restrict__ pool5)
{
    __shared__ float colsum[4][64];
    const int i = blockIdx.x, b = blockIdx.z;
    const int t = threadIdx.x;
    const int ch = t >> 6, w = t & 63;
    const int h0 = (i * 64) / 3, h1 = ((i + 1) * 64 + 2) / 3;
    const bool is4 = (blockIdx.y < 64);
    const int cg = is4 ? blockIdx.y : (blockIdx.y - 64);
    const int c = cg * 4 + ch;

    float s = 0.f;
    for (int h = h0; h < h1; ++h) {
        float v = is4 ? in4[(((size_t)b * 256 + c) * 64 + h) * 64 + w]
                      : in5[(((size_t)b * 512 + c) * 32 + (h >> 1)) * 32 + (w >> 1)];
        s += v;
    }
    colsum[ch][w] = s;
    __syncthreads();
    if (t < 12) {
        int c2 = t / 3, j = t % 3;
        int w0 = (j * 64) / 3, w1 = ((j + 1) * 64 + 2) / 3;
        float tot = 0.f;
        for (int x = w0; x < w1; ++x) tot += colsum[c2][x];
        float r = tot / (float)((h1 - h0) * (w1 - w0));
        if (is4) pool4[(((size_t)b * 256 + cg * 4 + c2) * 3 + i) * 3 + j] = r;
        else     pool5[(((size_t)b * 512 + cg * 4 + c2) * 3 + i) * 3 + j] = r;
    }
}

// ---------------------------------------------------------------------------
__global__ __launch_bounds__(64) void sim_mlp(
    const float* __restrict__ pool4, const float* __restrict__ pool5,
    const float* __restrict__ w4, const float* __restrict__ w5,
    const float* __restrict__ kgw1, const float* __restrict__ kgb1,
    const float* __restrict__ kgw2, const float* __restrict__ kgb2,
    const float* __restrict__ mask, float* __restrict__ kers)
{
    const int r = blockIdx.x, b = blockIdx.y, m = threadIdx.x;
    float p4 = 0.f, p5 = 0.f;
    for (int c = 0; c < C4_; ++c)
        p4 += w4[(size_t)m * C4_ + c] * pool4[((size_t)b * C4_ + c) * 9 + r];
    for (int c = 0; c < C5_; ++c)
        p5 += w5[(size_t)m * C5_ + c] * pool5[((size_t)b * C5_ + c) * 9 + r];
    float v = p4 * p5;
    #pragma unroll
    for (int off = 32; off; off >>= 1) v += __shfl_down(v, off);
    if (m == 0) {
        float g = v * (1.f / (1.f + __expf(-mask[r])));
        float hb[16];
        #pragma unroll
        for (int j = 0; j < 16; ++j) hb[j] = fmaxf(g * kgw1[j] + kgb1[j], 0.f);
        float lg[9], mx = -1e30f;
        #pragma unroll
        for (int k = 0; k < 9; ++k) {
            float s = kgb2[k];
            #pragma unroll
            for (int j = 0; j < 16; ++j) s += kgw2[k * 16 + j] * hb[j];
            lg[k] = s;
            mx = fmaxf(mx, s);
        }
        float den = 0.f;
        #pragma unroll
        for (int k = 0; k < 9; ++k) { lg[k] = __expf(lg[k] - mx); den += lg[k]; }
        float inv = 1.f / den;
        #pragma unroll
        for (int k = 0; k < 9; ++k)
            kers[((size_t)b * 9 + r) * 9 + k] = lg[k] * inv;
    }
}

// ---------------------------------------------------------------------------
// Dynamic 3x3 per-region conv, fused BN+SiLU, y read as bf16 NHWC,
// fused_red added from outb (bf16 NHWC), final out written fp32 NCHW (pure
// store, no read-modify-write).
// grid (H/8, 256/4, B), block 256 = 4ch x 64w
// ---------------------------------------------------------------------------
__global__ __launch_bounds__(256) void dynconv_bn(const u16* __restrict__ yb,
                                                  const u16* __restrict__ outb,
                                                  const float* __restrict__ ab,
                                                  const float* __restrict__ kers,
                                                  float* __restrict__ out)
{
    __shared__ float sX[4][10][66];
    __shared__ float sK[81];
    __shared__ float sAB[8];
    const int t = threadIdx.x;
    const int r0 = blockIdx.x * 8, cg = blockIdx.y, b = blockIdx.z;
    const int ch = t >> 6, w = t & 63;
    const int c = cg * 4 + ch;

    if (t < 4)      sAB[t] = ab[cg * 4 + t];
    else if (t < 8) sAB[t] = ab[252 + cg * 4 + t];   // 256 + cg*4 + (t-4)
    if (t < 81) sK[t] = kers[(size_t)b * 81 + t];
    __syncthreads();

    for (int idx = t; idx < 660; idx += 256) {
        int rr = idx / 66, cl = idx % 66;
        int gh = r0 - 1 + rr, gw = cl - 1;
        float v0 = 0.f, v1 = 0.f, v2 = 0.f, v3 = 0.f;
        if (gh >= 0 && gh < H_ && gw >= 0 && gw < W_) {
            ushort4 u = *(const ushort4*)&yb[((((size_t)b * 64 + gh) * 64 + gw) << 8) + cg * 4];
            float z;
            z = fmaf(sAB[0], b2f(u.x), sAB[4]); v0 = z / (1.f + __expf(-z));
            z = fmaf(sAB[1], b2f(u.y), sAB[5]); v1 = z / (1.f + __expf(-z));
            z = fmaf(sAB[2], b2f(u.z), sAB[6]); v2 = z / (1.f + __expf(-z));
            z = fmaf(sAB[3], b2f(u.w), sAB[7]); v3 = z / (1.f + __expf(-z));
        }
        sX[0][rr][cl] = v0;
        sX[1][rr][cl] = v1;
        sX[2][rr][cl] = v2;
        sX[3][rr][cl] = v3;
    }
    __syncthreads();

    const int rx = (w * 3) >> 6;
    for (int hh = 0; hh < 8; ++hh) {
        int h = r0 + hh;
        int ry = (h * 3) >> 6;
        const float* kp = &sK[(ry * 3 + rx) * 9];
        float acc = 0.f;
        #pragma unroll
        for (int dy = 0; dy < 3; ++dy)
            #pragma unroll
            for (int dx = 0; dx < 3; ++dx)
                acc += kp[dy * 3 + dx] * sX[ch][hh + dy][w + dx];
        acc += b2f(outb[((((size_t)b * 64 + h) * 64 + w) << 8) + c]);
        out[(((size_t)b * 256 + c) * H_ + h) * W_ + w] = acc;
    }
}

// ---------------------------------------------------------------------------
// Launch
// ---------------------------------------------------------------------------
extern "C" void kernel_launch(void* const* d_in, const int* in_sizes, int n_in,
                              void* d_out, int out_size, void* d_ws, size_t ws_size,
                              hipStream_t stream)
{
    const float* c4       = (const float*)d_in[0];
    const float* c5       = (const float*)d_in[1];
    const float* w_to_fuse= (const float*)d_in[2];
    const float* bn_gamma = (const float*)d_in[3];
    const float* bn_beta  = (const float*)d_in[4];
    const float* w_c4_proc= (const float*)d_in[5];
    const float* w_conv1  = (const float*)d_in[6];
    const float* w_reshape= (const float*)d_in[7];
    const float* w_proj   = (const float*)d_in[8];
    const float* w_sim4   = (const float*)d_in[9];
    const float* w_sim5   = (const float*)d_in[10];
    const float* kg_w1    = (const float*)d_in[11];
    const float* kg_b1    = (const float*)d_in[12];
    const float* kg_w2    = (const float*)d_in[13];
    const float* kg_b2    = (const float*)d_in[14];
    const float* mask_raw = (const float*)d_in[15];

    float* out = (float*)d_out;

    // workspace layout (u16 unless noted)
    u16*   yb    = (u16*)d_ws;                         // 8388608
    u16*   outb  = yb + 8388608;                       // 8388608
    u16*   fusedb= outb + 8388608;                     // 8388608
    u16*   c4t   = fusedb + 8388608;                   // 8388608
    u16*   c5t   = c4t + 8388608;                      // 4194304
    u16*   A3    = c5t + 4194304;                      // 589824
    u16*   A1    = A3 + 589824;                        // 131072
    u16*   Wtf   = A1 + 131072;                        // 65536
    u16*   Weff  = Wtf + 65536;                        // 65536
    float* pool4 = (float*)(Weff + 65536);             // 18432 f32
    float* pool5 = pool4 + 18432;                      // 36864 f32
    float* sums  = pool5 + 36864;                      // 512
    float* ab    = sums + 512;                         // 512
    float* kers  = ab + 512;                           // 648

    hipMemsetAsync(sums, 0, 512 * sizeof(float), stream);

    pack_misc<<<3328, 256, 0, stream>>>(w_c4_proc, w_conv1, w_to_fuse,
                                        w_proj, w_reshape, A3, A1, Wtf, Weff);
    pack_feat<<<dim3(96, 8), 256, 0, stream>>>(c4, c5, c4t, c5t);

    fuse_mfma<<<1024, 256, 25344, stream>>>(c4t, c5t, A3, A1, fusedb);

    gemm_cat<<<dim3(256, 4), 256, 0, stream>>>(fusedb, Wtf, Weff, yb, outb, sums);

    bn_finalize<<<1, 256, 0, stream>>>(sums, bn_gamma, bn_beta, ab);

    pool_both<<<dim3(3, 192, 8), 256, 0, stream>>>(c4, c5, pool4, pool5);

    sim_mlp<<<dim3(9, 8), 64, 0, stream>>>(pool4, pool5, w_sim4, w_sim5,
                                           kg_w1, kg_b1, kg_w2, kg_b2,
                                           mask_raw, kers);

    dynconv_bn<<<dim3(8, 64, 8), 256, 0, stream>>>(yb, outb, ab, kers, out);
}

// Round 8
// 265.925 us; speedup vs baseline: 1.1384x; 1.1384x over previous
//
#include <hip/hip_runtime.h>
#include <cstddef>

// Problem constants
#define B_   8
#define C4_  256
#define C5_  512
#define OC_  256
#define FR_  128
#define H_   64
#define W_   64
#define HW_  4096

typedef unsigned short u16;
typedef __bf16 bf16x8 __attribute__((ext_vector_type(8)));
typedef float floatx4 __attribute__((ext_vector_type(4)));

__device__ __forceinline__ u16 f2b(float x) {
    unsigned int u = __float_as_uint(x);
    return (u16)((u + 0x7FFFu + ((u >> 16) & 1u)) >> 16);
}
__device__ __forceinline__ float b2f(u16 x) {
    return __uint_as_float(((unsigned int)x) << 16);
}

// ---------------------------------------------------------------------------
// Merged weight packs + W_eff:
//  blocks 0..3071: A3[tap][oc][c] from w3; A1; Wtf  (786432 elems)
//  blocks 3072..3327: W_eff[oc][c] = sum_f w_proj[oc][f]*w_reshape[f][c]
// ---------------------------------------------------------------------------
__global__ __launch_bounds__(256) void pack_misc(
    const float* __restrict__ w3, const float* __restrict__ w1,
    const float* __restrict__ wtf,
    const float* __restrict__ wp, const float* __restrict__ wr,
    u16* __restrict__ A3, u16* __restrict__ A1, u16* __restrict__ Wtf,
    u16* __restrict__ Weff)
{
    if (blockIdx.x < 3072) {
        int i = blockIdx.x * 256 + threadIdx.x;
        if (i < 589824) {
            int tap = i >> 16;
            int r   = i & 65535;
            int oc  = r >> 8, c = r & 255;
            A3[i] = f2b(w3[((size_t)oc * 256 + c) * 9 + tap]);
        } else if (i < 720896) {
            int j = i - 589824;
            A1[j] = f2b(w1[j]);
        } else {
            int j = i - 720896;
            Wtf[j] = f2b(wtf[j]);
        }
    } else {
        const int oc = blockIdx.x - 3072, c = threadIdx.x;
        float s = 0.f;
        for (int f = 0; f < 128; ++f)
            s += wp[oc * 128 + f] * wr[f * 256 + c];
        Weff[oc * 256 + c] = f2b(s);
    }
}

// ---------------------------------------------------------------------------
// Merged feature packs: c4 NCHW f32 -> NHWC bf16 (x<64), c5 likewise (x>=64).
// grid (96, 8), block 256.
// ---------------------------------------------------------------------------
__global__ __launch_bounds__(256) void pack_feat(const float* __restrict__ in4,
                                                 const float* __restrict__ in5,
                                                 u16* __restrict__ c4t,
                                                 u16* __restrict__ c5t)
{
    __shared__ float sT[16448];
    const int t = threadIdx.x, b = blockIdx.y;
    if (blockIdx.x < 64) {
        const int h = blockIdx.x;
        const int w = t & 63, cg = t >> 6;          // cg 0..3
        for (int i = 0; i < 64; ++i) {
            int c = cg * 64 + i;
            sT[w * 257 + c] = in4[(((size_t)b * 256 + c) * 64 + h) * 64 + w];
        }
        __syncthreads();
        for (int i = 0; i < 16; ++i) {
            int ww = cg * 16 + i;
            int c0 = (t & 63) * 4;
            ushort4 v;
            v.x = f2b(sT[ww * 257 + c0]);
            v.y = f2b(sT[ww * 257 + c0 + 1]);
            v.z = f2b(sT[ww * 257 + c0 + 2]);
            v.w = f2b(sT[ww * 257 + c0 + 3]);
            *(ushort4*)&c4t[(((size_t)b * 64 + h) * 64 + ww) * 256 + c0] = v;
        }
    } else {
        const int h2 = blockIdx.x - 64;
        const int w = t & 31, cg = t >> 5;          // cg 0..7
        for (int i = 0; i < 64; ++i) {
            int c = cg * 64 + i;
            sT[w * 513 + c] = in5[(((size_t)b * 512 + c) * 32 + h2) * 32 + w];
        }
        __syncthreads();
        for (int i = 0; i < 16; ++i) {
            int id = i * 256 + t;                    // < 4096
            int ww = id >> 7, c0 = (id & 127) * 4;
            ushort4 v;
            v.x = f2b(sT[ww * 513 + c0]);
            v.y = f2b(sT[ww * 513 + c0 + 1]);
            v.z = f2b(sT[ww * 513 + c0 + 2]);
            v.w = f2b(sT[ww * 513 + c0 + 3]);
            *(ushort4*)&c5t[(((size_t)b * 32 + h2) * 32 + ww) * 512 + c0] = v;
        }
    }
}

// ---------------------------------------------------------------------------
// Fully fused MFMA kernel: per block (one output row h of one image b):
//  phase 1: fused[256ch][64px] = conv3x3(c4) + conv1x1(c5_up)  -> LDS (bf16)
//  phase 2: [y; fused_red] = [Wtf; Weff] @ fused  -> yb/outb (bf16 NHWC) +
//           BN sums for y.
// grid 512 (1-D, XCD-swizzled: one image per XCD), block 512 = 8 waves.
// LDS: 25344 B halo + 32768 B fused tile + 2048 B BN partials = 60160 B.
// ---------------------------------------------------------------------------
__global__ __launch_bounds__(512, 4) void fuse_all(
    const u16* __restrict__ c4t, const u16* __restrict__ c5t,
    const u16* __restrict__ A3, const u16* __restrict__ A1,
    const u16* __restrict__ Wtf, const u16* __restrict__ Weff,
    u16* __restrict__ yb, u16* __restrict__ outb, float* __restrict__ sums)
{
    extern __shared__ char smem[];
    char*  fusedT = smem + 25344;                   // 64 px * 512 B
    float* lsum   = (float*)(smem + 58112);         // 256
    float* lsq    = lsum + 256;                     // 256

    const int t   = threadIdx.x;
    const int lin = blockIdx.x;
    const int d   = ((lin & 7) << 6) + (lin >> 3);  // XCD-swizzle (512 blocks)
    const int b   = d >> 6;                         // image
    const int h   = d & 63;                         // output row

    const int l   = t & 63;
    const int w8  = t >> 6;                         // wave 0..7
    const int lr  = l & 15;
    const int ks  = l >> 4;                         // 0..3

    if (t < 256) { lsum[t] = 0.f; lsq[t] = 0.f; }

    floatx4 acc[2][4];
    #pragma unroll
    for (int m = 0; m < 2; ++m)
        #pragma unroll
        for (int n = 0; n < 4; ++n)
            acc[m][n] = (floatx4){0.f, 0.f, 0.f, 0.f};

    // ------------------- phase 1a: conv3x3, 4 chunks of 64 ch -------------------
    for (int c0 = 0; c0 < 256; c0 += 64) {
        __syncthreads();
        for (int i = t; i < 1584; i += 512) {       // 198 px * 8 segs
            int px  = i >> 3, seg = i & 7;
            int gh  = h - 1 + px / 66;
            int gw  = (px % 66) - 1;
            int4 v = {0, 0, 0, 0};
            if (gh >= 0 && gh < 64 && gw >= 0 && gw < 64)
                v = *(const int4*)(c4t + ((((size_t)b * 64 + gh) * 64 + gw) << 8) + c0 + seg * 8);
            *(int4*)(smem + px * 128 + ((seg ^ (px & 7)) << 4)) = v;
        }
        __syncthreads();

        #pragma unroll
        for (int ky = 0; ky < 3; ++ky) {
            #pragma unroll
            for (int kx = 0; kx < 3; ++kx) {
                const int tap = ky * 3 + kx;
                #pragma unroll
                for (int kk = 0; kk < 2; ++kk) {
                    bf16x8 a[2], bb[4];
                    #pragma unroll
                    for (int m = 0; m < 2; ++m) {
                        const int oc = w8 * 32 + m * 16 + lr;
                        a[m] = *(const bf16x8*)(A3 + (((size_t)tap * 256 + oc) * 256 + c0 + kk * 32 + ks * 8));
                    }
                    #pragma unroll
                    for (int n = 0; n < 4; ++n) {
                        const int pix = ky * 66 + n * 16 + lr + kx;
                        const int slot = ((kk << 2) + ks) ^ (pix & 7);
                        bb[n] = *(const bf16x8*)(smem + pix * 128 + slot * 16);
                    }
                    #pragma unroll
                    for (int m = 0; m < 2; ++m)
                        #pragma unroll
                        for (int n = 0; n < 4; ++n)
                            acc[m][n] = __builtin_amdgcn_mfma_f32_16x16x32_bf16(
                                a[m], bb[n], acc[m][n], 0, 0, 0);
                }
            }
        }
    }

    // ------------------- phase 1b: conv1x1 over c5_up, 16 chunks -------------------
    const int h2 = h >> 1;
    for (int cc = 0; cc < 512; cc += 32) {
        bf16x8 a[2], bb[4];
        #pragma unroll
        for (int m = 0; m < 2; ++m) {
            const int oc = w8 * 32 + m * 16 + lr;
            a[m] = *(const bf16x8*)(A1 + ((size_t)oc * 512 + cc + ks * 8));
        }
        #pragma unroll
        for (int n = 0; n < 4; ++n) {
            const int w2 = (n * 16 + lr) >> 1;
            bb[n] = *(const bf16x8*)(c5t + ((((size_t)b * 32 + h2) * 32 + w2) << 9) + cc + ks * 8);
        }
        #pragma unroll
        for (int m = 0; m < 2; ++m)
            #pragma unroll
            for (int n = 0; n < 4; ++n)
                acc[m][n] = __builtin_amdgcn_mfma_f32_16x16x32_bf16(
                    a[m], bb[n], acc[m][n], 0, 0, 0);
    }

    // ---- write fused tile to LDS as bf16, swizzled [px 64][ch-slot 32] ----
    // thread covers px = n*16+lr, oc = w8*32 + m*16 + ks*4 + r (r=0..3)
    #pragma unroll
    for (int n = 0; n < 4; ++n) {
        const int px = n * 16 + lr;
        #pragma unroll
        for (int m = 0; m < 2; ++m) {
            const int oc = w8 * 32 + m * 16 + ks * 4;
            const int slot = oc >> 3;
            ushort4 v;
            v.x = f2b(acc[m][n][0]);
            v.y = f2b(acc[m][n][1]);
            v.z = f2b(acc[m][n][2]);
            v.w = f2b(acc[m][n][3]);
            *(ushort4*)(fusedT + px * 512 + ((slot ^ (px & 7)) << 4) + (oc & 7) * 2) = v;
        }
    }
    __syncthreads();

    // ------------------- phase 2: [Wtf; Weff] @ fused (K=256) -------------------
    const u16* Wsel = (w8 < 4) ? Wtf : Weff;
    u16* dst        = (w8 < 4) ? yb : outb;
    const int wq    = w8 & 3;                       // 64-row slice within output

    #pragma unroll
    for (int hf = 0; hf < 2; ++hf) {                // two 32-row halves
        floatx4 a2[2][4];
        #pragma unroll
        for (int m = 0; m < 2; ++m)
            #pragma unroll
            for (int n = 0; n < 4; ++n)
                a2[m][n] = (floatx4){0.f, 0.f, 0.f, 0.f};

        for (int c0 = 0; c0 < 256; c0 += 32) {
            bf16x8 a[2], bb[4];
            #pragma unroll
            for (int m = 0; m < 2; ++m) {
                const int row = wq * 64 + hf * 32 + m * 16 + lr;
                a[m] = *(const bf16x8*)(Wsel + (size_t)row * 256 + c0 + ks * 8);
            }
            #pragma unroll
            for (int n = 0; n < 4; ++n) {
                const int px = n * 16 + lr;
                const int kslot = (c0 >> 3) + ks;
                bb[n] = *(const bf16x8*)(fusedT + px * 512 + ((kslot ^ (px & 7)) << 4));
            }
            #pragma unroll
            for (int m = 0; m < 2; ++m)
                #pragma unroll
                for (int n = 0; n < 4; ++n)
                    a2[m][n] = __builtin_amdgcn_mfma_f32_16x16x32_bf16(
                        a[m], bb[n], a2[m][n], 0, 0, 0);
        }

        // epilogue: bf16 NHWC + BN partial sums (y rows only)
        #pragma unroll
        for (int n = 0; n < 4; ++n) {
            const int px = n * 16 + lr;
            const size_t gp = (((size_t)b * 64 + h) * 64 + px) * 256;
            #pragma unroll
            for (int m = 0; m < 2; ++m) {
                const int ocl = wq * 64 + hf * 32 + m * 16 + ks * 4;
                ushort4 v;
                v.x = f2b(a2[m][n][0]);
                v.y = f2b(a2[m][n][1]);
                v.z = f2b(a2[m][n][2]);
                v.w = f2b(a2[m][n][3]);
                *(ushort4*)&dst[gp + ocl] = v;
            }
        }
        if (w8 < 4) {
            #pragma unroll
            for (int m = 0; m < 2; ++m) {
                #pragma unroll
                for (int r = 0; r < 4; ++r) {
                    float s = 0.f, q = 0.f;
                    #pragma unroll
                    for (int n = 0; n < 4; ++n) {
                        float v = a2[m][n][r];
                        s += v; q += v * v;
                    }
                    #pragma unroll
                    for (int off = 1; off < 16; off <<= 1) {
                        s += __shfl_xor(s, off);
                        q += __shfl_xor(q, off);
                    }
                    if (lr == 0) {
                        const int ocl = wq * 64 + hf * 32 + m * 16 + ks * 4 + r;
                        atomicAdd(&lsum[ocl], s);
                        atomicAdd(&lsq[ocl], q);
                    }
                }
            }
        }
    }

    __syncthreads();
    if (t < 256) {
        atomicAdd(&sums[t], lsum[t]);
        atomicAdd(&sums[256 + t], lsq[t]);
    }
}

// ---------------------------------------------------------------------------
// Merged adaptive pools: cg<64 -> pool4 from c4; else pool5 from c5 upsampled.
// grid (3, 192, 8), block 256 = 4ch x 64w
// ---------------------------------------------------------------------------
__global__ __launch_bounds__(256) void pool_both(const float* __restrict__ in4,
                                                 const float* __restrict__ in5,
                                                 float* __restrict__ pool4,
                                                 float* __restrict__ pool5)
{
    __shared__ float colsum[4][64];
    const int i = blockIdx.x, b = blockIdx.z;
    const int t = threadIdx.x;
    const int ch = t >> 6, w = t & 63;
    const int h0 = (i * 64) / 3, h1 = ((i + 1) * 64 + 2) / 3;
    const bool is4 = (blockIdx.y < 64);
    const int cg = is4 ? blockIdx.y : (blockIdx.y - 64);
    const int c = cg * 4 + ch;

    float s = 0.f;
    for (int h = h0; h < h1; ++h) {
        float v = is4 ? in4[(((size_t)b * 256 + c) * 64 + h) * 64 + w]
                      : in5[(((size_t)b * 512 + c) * 32 + (h >> 1)) * 32 + (w >> 1)];
        s += v;
    }
    colsum[ch][w] = s;
    __syncthreads();
    if (t < 12) {
        int c2 = t / 3, j = t % 3;
        int w0 = (j * 64) / 3, w1 = ((j + 1) * 64 + 2) / 3;
        float tot = 0.f;
        for (int x = w0; x < w1; ++x) tot += colsum[c2][x];
        float r = tot / (float)((h1 - h0) * (w1 - w0));
        if (is4) pool4[(((size_t)b * 256 + cg * 4 + c2) * 3 + i) * 3 + j] = r;
        else     pool5[(((size_t)b * 512 + cg * 4 + c2) * 3 + i) * 3 + j] = r;
    }
}

// ---------------------------------------------------------------------------
__global__ __launch_bounds__(64) void sim_mlp(
    const float* __restrict__ pool4, const float* __restrict__ pool5,
    const float* __restrict__ w4, const float* __restrict__ w5,
    const float* __restrict__ kgw1, const float* __restrict__ kgb1,
    const float* __restrict__ kgw2, const float* __restrict__ kgb2,
    const float* __restrict__ mask, float* __restrict__ kers)
{
    const int r = blockIdx.x, b = blockIdx.y, m = threadIdx.x;
    float p4 = 0.f, p5 = 0.f;
    for (int c = 0; c < C4_; ++c)
        p4 += w4[(size_t)m * C4_ + c] * pool4[((size_t)b * C4_ + c) * 9 + r];
    for (int c = 0; c < C5_; ++c)
        p5 += w5[(size_t)m * C5_ + c] * pool5[((size_t)b * C5_ + c) * 9 + r];
    float v = p4 * p5;
    #pragma unroll
    for (int off = 32; off; off >>= 1) v += __shfl_down(v, off);
    if (m == 0) {
        float g = v * (1.f / (1.f + __expf(-mask[r])));
        float hb[16];
        #pragma unroll
        for (int j = 0; j < 16; ++j) hb[j] = fmaxf(g * kgw1[j] + kgb1[j], 0.f);
        float lg[9], mx = -1e30f;
        #pragma unroll
        for (int k = 0; k < 9; ++k) {
            float s = kgb2[k];
            #pragma unroll
            for (int j = 0; j < 16; ++j) s += kgw2[k * 16 + j] * hb[j];
            lg[k] = s;
            mx = fmaxf(mx, s);
        }
        float den = 0.f;
        #pragma unroll
        for (int k = 0; k < 9; ++k) { lg[k] = __expf(lg[k] - mx); den += lg[k]; }
        float inv = 1.f / den;
        #pragma unroll
        for (int k = 0; k < 9; ++k)
            kers[((size_t)b * 9 + r) * 9 + k] = lg[k] * inv;
    }
}

// ---------------------------------------------------------------------------
// Dynamic 3x3 per-region conv, fused BN (coefficients derived in-block from
// sums) + SiLU, y read as bf16 NHWC, fused_red added from outb, out written
// fp32 NCHW (pure store).
// grid (H/8, 256/4, B), block 256 = 4ch x 64w
// ---------------------------------------------------------------------------
__global__ __launch_bounds__(256) void dynconv_bn(const u16* __restrict__ yb,
                                                  const u16* __restrict__ outb,
                                                  const float* __restrict__ sums,
                                                  const float* __restrict__ gamma,
                                                  const float* __restrict__ beta,
                                                  const float* __restrict__ kers,
                                                  float* __restrict__ out)
{
    __shared__ float sX[4][10][66];
    __shared__ float sK[81];
    __shared__ float sAB[8];
    const int t = threadIdx.x;
    const int r0 = blockIdx.x * 8, cg = blockIdx.y, b = blockIdx.z;
    const int ch = t >> 6, w = t & 63;
    const int c = cg * 4 + ch;

    if (t < 4) {
        const int cc = cg * 4 + t;
        const float n = (float)(B_ * HW_);
        float mu  = sums[cc] / n;
        float var = sums[256 + cc] / n - mu * mu;
        float a = gamma[cc] * rsqrtf(var + 1e-5f);
        sAB[t]     = a;
        sAB[4 + t] = beta[cc] - mu * a;
    }
    if (t < 81) sK[t] = kers[(size_t)b * 81 + t];
    __syncthreads();

    for (int idx = t; idx < 660; idx += 256) {
        int rr = idx / 66, cl = idx % 66;
        int gh = r0 - 1 + rr, gw = cl - 1;
        float v0 = 0.f, v1 = 0.f, v2 = 0.f, v3 = 0.f;
        if (gh >= 0 && gh < H_ && gw >= 0 && gw < W_) {
            ushort4 u = *(const ushort4*)&yb[((((size_t)b * 64 + gh) * 64 + gw) << 8) + cg * 4];
            float z;
            z = fmaf(sAB[0], b2f(u.x), sAB[4]); v0 = z / (1.f + __expf(-z));
            z = fmaf(sAB[1], b2f(u.y), sAB[5]); v1 = z / (1.f + __expf(-z));
            z = fmaf(sAB[2], b2f(u.z), sAB[6]); v2 = z / (1.f + __expf(-z));
            z = fmaf(sAB[3], b2f(u.w), sAB[7]); v3 = z / (1.f + __expf(-z));
        }
        sX[0][rr][cl] = v0;
        sX[1][rr][cl] = v1;
        sX[2][rr][cl] = v2;
        sX[3][rr][cl] = v3;
    }
    __syncthreads();

    const int rx = (w * 3) >> 6;
    for (int hh = 0; hh < 8; ++hh) {
        int h = r0 + hh;
        int ry = (h * 3) >> 6;
        const float* kp = &sK[(ry * 3 + rx) * 9];
        float acc = 0.f;
        #pragma unroll
        for (int dy = 0; dy < 3; ++dy)
            #pragma unroll
            for (int dx = 0; dx < 3; ++dx)
                acc += kp[dy * 3 + dx] * sX[ch][hh + dy][w + dx];
        acc += b2f(outb[((((size_t)b * 64 + h) * 64 + w) << 8) + c]);
        out[(((size_t)b * 256 + c) * H_ + h) * W_ + w] = acc;
    }
}

// ---------------------------------------------------------------------------
// Launch
// ---------------------------------------------------------------------------
extern "C" void kernel_launch(void* const* d_in, const int* in_sizes, int n_in,
                              void* d_out, int out_size, void* d_ws, size_t ws_size,
                              hipStream_t stream)
{
    const float* c4       = (const float*)d_in[0];
    const float* c5       = (const float*)d_in[1];
    const float* w_to_fuse= (const float*)d_in[2];
    const float* bn_gamma = (const float*)d_in[3];
    const float* bn_beta  = (const float*)d_in[4];
    const float* w_c4_proc= (const float*)d_in[5];
    const float* w_conv1  = (const float*)d_in[6];
    const float* w_reshape= (const float*)d_in[7];
    const float* w_proj   = (const float*)d_in[8];
    const float* w_sim4   = (const float*)d_in[9];
    const float* w_sim5   = (const float*)d_in[10];
    const float* kg_w1    = (const float*)d_in[11];
    const float* kg_b1    = (const float*)d_in[12];
    const float* kg_w2    = (const float*)d_in[13];
    const float* kg_b2    = (const float*)d_in[14];
    const float* mask_raw = (const float*)d_in[15];

    float* out = (float*)d_out;

    // workspace layout (u16 unless noted)
    u16*   yb    = (u16*)d_ws;                         // 8388608
    u16*   outb  = yb + 8388608;                       // 8388608
    u16*   c4t   = outb + 8388608;                     // 8388608
    u16*   c5t   = c4t + 8388608;                      // 4194304
    u16*   A3    = c5t + 4194304;                      // 589824
    u16*   A1    = A3 + 589824;                        // 131072
    u16*   Wtf   = A1 + 131072;                        // 65536
    u16*   Weff  = Wtf + 65536;                        // 65536
    float* pool4 = (float*)(Weff + 65536);             // 18432 f32
    float* pool5 = pool4 + 18432;                      // 36864 f32
    float* sums  = pool5 + 36864;                      // 512
    float* kers  = sums + 512;                         // 648

    hipMemsetAsync(sums, 0, 512 * sizeof(float), stream);

    pack_misc<<<3328, 256, 0, stream>>>(w_c4_proc, w_conv1, w_to_fuse,
                                        w_proj, w_reshape, A3, A1, Wtf, Weff);
    pack_feat<<<dim3(96, 8), 256, 0, stream>>>(c4, c5, c4t, c5t);

    fuse_all<<<512, 512, 60160, stream>>>(c4t, c5t, A3, A1, Wtf, Weff,
                                          yb, outb, sums);

    pool_both<<<dim3(3, 192, 8), 256, 0, stream>>>(c4, c5, pool4, pool5);

    sim_mlp<<<dim3(9, 8), 64, 0, stream>>>(pool4, pool5, w_sim4, w_sim5,
                                           kg_w1, kg_b1, kg_w2, kg_b2,
                                           mask_raw, kers);

    dynconv_bn<<<dim3(8, 64, 8), 256, 0, stream>>>(yb, outb, sums,
                                                   bn_gamma, bn_beta, kers, out);
}